// Round 9
// baseline (859.140 us; speedup 1.0000x reference)
//
#include <hip/hip_runtime.h>

// RGCN link predictor, aggregate-first formulation:
//   out[i] = sum_r W_r @ mean_{j in N_r(i)} x_j + root@x_i + b
// Edges bucketed by (64-dst-block, rel); per block the per-relation mean
// vectors are accumulated in LDS (f32 atomics) from the bf16 input table,
// then MFMA-multiplied by pre-swizzled W_r fragments, all relations + root
// accumulating into one AGPR accumulator. No per-relation H table exists.
//
// Output layout: direct permuted C-store, true-col pi(q)=(q%CT)*16+q/CT at
// short-position q. hmid inherits pi64 (W2/root2 k-rows pre-permuted), z
// inherits pi32 (decode dot invariant), bias folded in epilogue.
//
// Problem sizes fixed by harness: N=100000, E=1e6 uniform, NREL=8.
// 512-dst buckets: 196, ~5120 edges each (sigma~72); SCAP=+14sigma.
#define F_IN 64
#define F_HID 64
#define F_OUT 32
#define NREL 8
#define SCAP 6144    // staging capacity per 512-bucket (edges)
#define RCAP2 6528   // rec capacity per bucket (edges + 64 segs * 3 pad)
#define MAXBUCK 200
#define PA_PE 16     // edges per thread in binA

typedef __attribute__((ext_vector_type(8))) short bfrag;   // 8 bf16 (A/B frag)
typedef __attribute__((ext_vector_type(4))) float ffrag;   // 4 f32  (C/D frag)

// ---------------------------------------------------------------------------
// bf16 helpers (manual RNE pack)
__device__ inline unsigned short f2bf(float f) {
  unsigned u = __float_as_uint(f);
  unsigned r = (u + 0x7fffu + ((u >> 16) & 1u)) >> 16;
  return (unsigned short)r;
}
__device__ inline unsigned bf16pair(float lo, float hi) {
  return (unsigned)f2bf(lo) | ((unsigned)f2bf(hi) << 16);
}
__device__ inline float bflo(unsigned u) { return __uint_as_float(u << 16); }
__device__ inline float bfhi(unsigned u) { return __uint_as_float(u & 0xffff0000u); }
__device__ inline float dot8(uint4 a, uint4 b) {
  return bflo(a.x) * bflo(b.x) + bfhi(a.x) * bfhi(b.x) +
         bflo(a.y) * bflo(b.y) + bfhi(a.y) * bfhi(b.y) +
         bflo(a.z) * bflo(b.z) + bfhi(a.z) * bfhi(b.z) +
         bflo(a.w) * bflo(b.w) + bfhi(a.w) * bfhi(b.w);
}

// ---------------------------------------------------------------------------
// Fused prep: weight fragment swizzle for both layers (+root slots) + gcur.
// Fragment slot j at lane l holds Wsrc[kperm(k0+j)][c*16+(l&15)],
// k0 = s*32+(l>>4)*8. PERMK applies pi64 (layer 2: A operand is permuted).
template <int O, bool PERMK>
__device__ inline void wprep_one(int t, const float* __restrict__ W,
                                 const float* __restrict__ root,
                                 unsigned short* __restrict__ Wf) {
  constexpr int CT = O / 16;
  int l = t & 63;
  int s = (t >> 6) & 1;
  int rc = t >> 7;
  int c = rc % CT;
  int r = rc / CT;
  const float* wsrc = (r < NREL) ? W + (size_t)r * 64 * O : root;
  unsigned short* dst = Wf + (size_t)t * 8;
  int col = c * 16 + (l & 15);
  int k0 = s * 32 + ((l >> 4) * 8);
#pragma unroll
  for (int j = 0; j < 8; ++j) {
    int k = k0 + j;
    if (PERMK) k = (k & 3) * 16 + (k >> 2);   // pi64
    dst[j] = f2bf(wsrc[(size_t)k * O + col]);
  }
}

__global__ __launch_bounds__(256) void prep_kernel(
    const float* __restrict__ W1, const float* __restrict__ root1,
    const float* __restrict__ W2, const float* __restrict__ root2,
    unsigned short* __restrict__ wf1, unsigned short* __restrict__ wf2,
    int* __restrict__ gcur, int nbuck) {
  int gid = blockIdx.x * 256 + threadIdx.x;
  const int J1 = (NREL + 1) * (F_HID / 16) * 2 * 64;  // 4608
  const int J2 = (NREL + 1) * (F_OUT / 16) * 2 * 64;  // 2304
  if (gid < J1) {
    wprep_one<F_HID, false>(gid, W1, root1, wf1);
  } else if (gid < J1 + J2) {
    wprep_one<F_OUT, true>(gid - J1, W2, root2, wf2);
  } else if (gid - J1 - J2 < nbuck) {
    int b = gid - J1 - J2;
    gcur[b] = b * SCAP;
  }
}

// f32 -> bf16 conversion, 8 elements/thread
__global__ __launch_bounds__(256) void cvt_bf16_kernel(
    const float* __restrict__ in, unsigned* __restrict__ out, int n8) {
  int i = blockIdx.x * blockDim.x + threadIdx.x;
  if (i >= n8) return;
  const float4* p = (const float4*)(in + (size_t)i * 8);
  float4 a = p[0], b = p[1];
  uint4 o;
  o.x = bf16pair(a.x, a.y);
  o.y = bf16pair(a.z, a.w);
  o.z = bf16pair(b.x, b.y);
  o.w = bf16pair(b.z, b.w);
  *((uint4*)out + i) = o;
}

// ---------------------------------------------------------------------------
// Pass A: bin edges by 512-dst bucket into per-bucket staging regions.
// Pack: src (17b) | rel (3b, bit17) | dstLow9 (bit20).
__global__ __launch_bounds__(256) void binA_kernel(
    const int* __restrict__ src, const int* __restrict__ dst,
    const int* __restrict__ et, int* __restrict__ gcur,
    unsigned* __restrict__ staging, int E) {
  __shared__ int hist[MAXBUCK * 4];
  __shared__ int wbase[MAXBUCK * 4];
  const int tid = threadIdx.x;
  const int wave = tid >> 6;
  for (int i = tid; i < MAXBUCK * 4; i += 256) hist[i] = 0;
  __syncthreads();
  const int base = blockIdx.x * (256 * PA_PE);
  int dv[PA_PE], rk[PA_PE];
#pragma unroll
  for (int j = 0; j < PA_PE; ++j) {
    int e = base + j * 256 + tid;
    if (e < E) {
      int d = dst[e];
      dv[j] = d;
      rk[j] = atomicAdd(&hist[(d >> 9) * 4 + wave], 1);
    } else {
      dv[j] = -1;
    }
  }
  __syncthreads();
  for (int b = tid; b < MAXBUCK; b += 256) {
    int h0 = hist[b * 4 + 0], h1 = hist[b * 4 + 1];
    int h2 = hist[b * 4 + 2], h3 = hist[b * 4 + 3];
    int tot = h0 + h1 + h2 + h3;
    int gb = tot ? atomicAdd(&gcur[b], tot) : 0;
    wbase[b * 4 + 0] = gb;
    wbase[b * 4 + 1] = gb + h0;
    wbase[b * 4 + 2] = gb + h0 + h1;
    wbase[b * 4 + 3] = gb + h0 + h1 + h2;
  }
  __syncthreads();
#pragma unroll
  for (int j = 0; j < PA_PE; ++j) {
    if (dv[j] >= 0) {
      int e = base + j * 256 + tid;
      unsigned pk = (unsigned)src[e] | ((unsigned)et[e] << 17) |
                    ((unsigned)(dv[j] & 511) << 20);
      staging[wbase[(dv[j] >> 9) * 4 + wave] + rk[j]] = pk;
    }
  }
}

// Pass B: one block per 512-bucket. Per-(dstLocal,rel) counts in LDS
// (-> pinv); edges regrouped into 64 segments = (8 sub-blocks of 64 dsts) x
// (8 rels), each padded to a multiple of 4. Record: {src|dstLoc6<<17, pinv}.
__global__ __launch_bounds__(256) void binB_kernel(
    const unsigned* __restrict__ staging, const int* __restrict__ gcur,
    int2* __restrict__ rec, int* __restrict__ segS, int* __restrict__ segE,
    int N) {
  __shared__ int cnt8[512 * 8];   // counts, then reused as pinv (float bits)
  __shared__ int segp[64], segt[64], segEl[64], cur[64];
  const int b = blockIdx.x;
  const int tid = threadIdx.x;
  const int cnt_b = gcur[b] - b * SCAP;
  const unsigned* st = staging + (size_t)b * SCAP;
  for (int i = tid; i < 512 * 8; i += 256) cnt8[i] = 0;
  __syncthreads();
  for (int i = tid; i < cnt_b; i += 256) {
    unsigned e = st[i];
    atomicAdd(&cnt8[((e >> 20) & 511) * 8 + ((e >> 17) & 7)], 1);
  }
  __syncthreads();
  if (tid < 64) {           // seg (sb,r): tot = sum over 64 dsts
    int sb = tid >> 3, r = tid & 7;
    int tot = 0;
#pragma unroll 8
    for (int j = 0; j < 64; ++j) tot += cnt8[((sb << 6) + j) * 8 + r];
    segp[tid] = (tot + 3) & ~3;
  }
  __syncthreads();
  if (tid == 0) {           // exclusive scan of 64 padded totals
    int run = 0;
    for (int s = 0; s < 64; ++s) { segt[s] = run; run += segp[s]; }
  }
  __syncthreads();
  if (tid < 64) {
    int s0 = b * RCAP2 + segt[tid];
    int e0 = s0 + segp[tid];
    segS[b * 64 + tid] = s0;
    segE[b * 64 + tid] = e0;
    segEl[tid] = e0;
    cur[tid] = s0;
  }
  __syncthreads();
  for (int i = tid; i < 512 * 8; i += 256) {   // counts -> pinv (in place)
    int cc = cnt8[i];
    ((float*)cnt8)[i] = cc > 0 ? 1.0f / (float)cc : 0.0f;
  }
  __syncthreads();
  for (int i = tid; i < cnt_b; i += 256) {
    unsigned e = st[i];
    int s = e & 0x1FFFF;
    int r = (e >> 17) & 7;
    int dl = (e >> 20) & 511;
    int pos = atomicAdd(&cur[(dl >> 6) * 8 + r], 1);
    rec[pos] = make_int2(s | ((dl & 63) << 17), cnt8[dl * 8 + r]);
  }
  __syncthreads();
  if (tid < 64)
    for (int p = cur[tid]; p < segEl[tid]; ++p) rec[p] = make_int2(0, 0);
}

// ---------------------------------------------------------------------------
// Aggregate-first fused layer: block = 64 dst nodes, 256 threads (4 waves).
// For each rel: LDS-accumulate mean vectors (f32 atomics, pinv-scaled bf16
// gathers from X), then acc += A_r @ W_r (MFMA). Root + bias + (ReLU) in
// epilogue; direct permuted bf16 store.
template <int O, bool RELU>
__global__ __launch_bounds__(256) void ragg_kernel(
    const unsigned short* __restrict__ X,   // input table [.][64] bf16
    const unsigned short* __restrict__ Wf,  // 9 fragment slots
    const int* __restrict__ segS, const int* __restrict__ segE,
    const int2* __restrict__ rec, const float* __restrict__ bias,
    unsigned short* __restrict__ Y, int N) {
  constexpr int CT = O / 16;
  __shared__ float A[64][68];               // +4 pad: 2-way banks only
  const int tid = threadIdx.x;
  const int w = tid >> 6, l = tid & 63;
  const int blk = blockIdx.x;
  ffrag acc[CT];
#pragma unroll
  for (int c = 0; c < CT; ++c) acc[c] = (ffrag){0.f, 0.f, 0.f, 0.f};
  const int ec = tid >> 3;   // edge slot 0..31
  const int ch = tid & 7;    // feature chunk (8 bf16)
  for (int r = 0; r < NREL; ++r) {
    for (int i = tid; i < 64 * 68 / 4; i += 256)
      ((float4*)A)[i] = make_float4(0.f, 0.f, 0.f, 0.f);
    __syncthreads();
    const int p1 = segE[blk * 8 + r];
    for (int p = segS[blk * 8 + r] + ec; p < p1; p += 32) {
      int2 rcd = rec[p];
      int sidx = rcd.x & 0x1FFFF;
      int dl = (rcd.x >> 17) & 63;
      float pv = __int_as_float(rcd.y);
      uint4 g = *(const uint4*)(X + (size_t)sidx * 64 + ch * 8);
      float* ap = &A[dl][ch * 8];
      atomicAdd(ap + 0, pv * bflo(g.x)); atomicAdd(ap + 1, pv * bfhi(g.x));
      atomicAdd(ap + 2, pv * bflo(g.y)); atomicAdd(ap + 3, pv * bfhi(g.y));
      atomicAdd(ap + 4, pv * bflo(g.z)); atomicAdd(ap + 5, pv * bfhi(g.z));
      atomicAdd(ap + 6, pv * bflo(g.w)); atomicAdd(ap + 7, pv * bfhi(g.w));
    }
    __syncthreads();
    const float* ap = &A[w * 16 + (l & 15)][(l >> 4) * 8];
    float4 f0 = *(const float4*)(ap);
    float4 f1 = *(const float4*)(ap + 4);
    float4 f2 = *(const float4*)(ap + 32);
    float4 f3 = *(const float4*)(ap + 36);
    uint4 ua, ub;
    ua.x = bf16pair(f0.x, f0.y); ua.y = bf16pair(f0.z, f0.w);
    ua.z = bf16pair(f1.x, f1.y); ua.w = bf16pair(f1.z, f1.w);
    ub.x = bf16pair(f2.x, f2.y); ub.y = bf16pair(f2.z, f2.w);
    ub.z = bf16pair(f3.x, f3.y); ub.w = bf16pair(f3.z, f3.w);
    bfrag a0 = *(bfrag*)&ua, a1 = *(bfrag*)&ub;
    const unsigned short* wb = Wf + ((size_t)r * CT * 2 * 64 + l) * 8;
#pragma unroll
    for (int c = 0; c < CT; ++c) {
      bfrag b0 = *(const bfrag*)(wb + (size_t)(c * 2 + 0) * 512);
      bfrag b1 = *(const bfrag*)(wb + (size_t)(c * 2 + 1) * 512);
      acc[c] = __builtin_amdgcn_mfma_f32_16x16x32_bf16(a0, b0, acc[c], 0, 0, 0);
      acc[c] = __builtin_amdgcn_mfma_f32_16x16x32_bf16(a1, b1, acc[c], 0, 0, 0);
    }
    __syncthreads();
  }
  // root term (slot 8): operand = own row of X
  int arow = blk * 64 + w * 16 + (l & 15);
  if (arow >= N) arow = N - 1;
  const unsigned short* xp = X + (size_t)arow * 64 + ((l >> 4) * 8);
  bfrag a0 = *(const bfrag*)(xp);
  bfrag a1 = *(const bfrag*)(xp + 32);
  const unsigned short* wb = Wf + ((size_t)NREL * CT * 2 * 64 + l) * 8;
#pragma unroll
  for (int c = 0; c < CT; ++c) {
    bfrag b0 = *(const bfrag*)(wb + (size_t)(c * 2 + 0) * 512);
    bfrag b1 = *(const bfrag*)(wb + (size_t)(c * 2 + 1) * 512);
    acc[c] = __builtin_amdgcn_mfma_f32_16x16x32_bf16(a0, b0, acc[c], 0, 0, 0);
    acc[c] = __builtin_amdgcn_mfma_f32_16x16x32_bf16(a1, b1, acc[c], 0, 0, 0);
  }
  // epilogue: bias (true col = c*16 + (l&15)), ReLU, permuted bf16 store
  float bv[CT];
#pragma unroll
  for (int c = 0; c < CT; ++c) bv[c] = bias[c * 16 + (l & 15)];
  const int rbase = blk * 64 + w * 16 + ((l >> 4) << 2);
#pragma unroll
  for (int i = 0; i < 4; ++i) {
    int row = rbase + i;
    if (row < N) {
      float v[CT];
#pragma unroll
      for (int c = 0; c < CT; ++c) {
        v[c] = acc[c][i] + bv[c];
        if (RELU) v[c] = fmaxf(v[c], 0.f);
      }
      if (O == 64) {
        uint2 o;
        o.x = bf16pair(v[0], v[1]);
        o.y = bf16pair(v[2], v[3]);
        *(uint2*)(Y + (size_t)row * 64 + (l & 15) * 4) = o;
      } else {
        *(unsigned*)(Y + (size_t)row * 32 + (l & 15) * 2) = bf16pair(v[0], v[1]);
      }
    }
  }
}

// ---------------------------------------------------------------------------
// Decode: out[e] = dot(z[src[e]], z[dst[e]]) over 32 bf16 features (pi32-
// permuted on both operands -> invariant).
__global__ __launch_bounds__(256) void decode_kernel(
    const unsigned* __restrict__ Z, const int* __restrict__ src,
    const int* __restrict__ dst, float* __restrict__ out, int E) {
  int e = blockIdx.x * blockDim.x + threadIdx.x;
  if (e >= E) return;
  const uint4* zs = (const uint4*)(Z + (size_t)src[e] * 16);
  const uint4* zd = (const uint4*)(Z + (size_t)dst[e] * 16);
  uint4 a0 = zs[0], a1 = zs[1], a2 = zs[2], a3 = zs[3];
  uint4 b0 = zd[0], b1 = zd[1], b2 = zd[2], b3 = zd[3];
  out[e] = dot8(a0, b0) + dot8(a1, b1) + dot8(a2, b2) + dot8(a3, b3);
}

// ---------------------------------------------------------------------------
extern "C" void kernel_launch(void* const* d_in, const int* in_sizes, int n_in,
                              void* d_out, int out_size, void* d_ws, size_t ws_size,
                              hipStream_t stream) {
  const float* x     = (const float*)d_in[0];
  const float* W1    = (const float*)d_in[1];
  const float* root1 = (const float*)d_in[2];
  const float* b1    = (const float*)d_in[3];
  const float* W2    = (const float*)d_in[4];
  const float* root2 = (const float*)d_in[5];
  const float* b2    = (const float*)d_in[6];
  const int*   ei    = (const int*)d_in[7];   // [2, E] int32
  const int*   et    = (const int*)d_in[8];   // [E] int32

  const int N = in_sizes[0] / F_IN;           // 100000
  const int E = in_sizes[8];                  // 1000000
  const int nbuck = (N + 511) >> 9;           // 196
  const int nblk64 = nbuck * 8;               // 1568 (64-dst blocks)
  const int* srcp = ei;
  const int* dstp = ei + E;

  // Workspace layout (bytes), peak ~47 MB
  char* ws = (char*)d_ws;
  int*            gcur    = (int*)(ws + 0);              //  800 B [nbuck]
  unsigned*       staging = (unsigned*)(ws + 4096);      //  4.9 MB [200*SCAP]
  int*            segS    = (int*)(ws + 4919296);        //  50 KB [nbuck*64]
  int*            segE    = (int*)(ws + 4969472);        //  50 KB
  int2*           rec     = (int2*)(ws + 5019648);       // 10.2 MB [nbuck*RCAP2]
  unsigned short* wf1     = (unsigned short*)(ws + 15255552);  // 73.7 KB (9 slots)
  unsigned short* wf2     = (unsigned short*)(ws + 15329280);  // 36.9 KB (9 slots)
  unsigned short* xb      = (unsigned short*)(ws + 15366144);  // 12.8 MB bf16[N*64]
  unsigned short* hmid    = (unsigned short*)(ws + 28166144);  // 12.8 MB bf16[N*64]
  unsigned short* z       = (unsigned short*)(ws + 40966144);  //  6.4 MB bf16[N*32]

  // ---- prep (wf1, wf2, gcur) + x->bf16 + bucketed 2-pass CSR build ----
  prep_kernel<<<28, 256, 0, stream>>>(W1, root1, W2, root2, wf1, wf2, gcur, nbuck);
  cvt_bf16_kernel<<<(N * (F_IN / 8) + 255) / 256, 256, 0, stream>>>(
      x, (unsigned*)xb, N * (F_IN / 8));
  binA_kernel<<<(E + 256 * PA_PE - 1) / (256 * PA_PE), 256, 0, stream>>>(
      srcp, dstp, et, gcur, staging, E);
  binB_kernel<<<nbuck, 256, 0, stream>>>(staging, gcur, rec, segS, segE, N);

  // ---- Layer 1: xb -> hmid (bf16, pi64) ----
  ragg_kernel<F_HID, true>
      <<<nblk64, 256, 0, stream>>>(xb, wf1, segS, segE, rec, b1, hmid, N);

  // ---- Layer 2: hmid -> z (bf16, pi32) ----
  ragg_kernel<F_OUT, false>
      <<<nblk64, 256, 0, stream>>>(hmid, wf2, segS, segE, rec, b2, z, N);

  // ---- Decode ----
  decode_kernel<<<(E + 255) / 256, 256, 0, stream>>>((const unsigned*)z, srcp, dstp,
                                                     (float*)d_out, E);
}

// Round 10
// 474.339 us; speedup vs baseline: 1.8112x; 1.8112x over previous
//
#include <hip/hip_runtime.h>

// RGCN link predictor, aggregate-first formulation (round-9 structure,
// atomic-free aggregation):
//   out[i] = sum_r W_r @ mean_{j in N_r(i)} x_j + root@x_i + b
// Edges bucketed by (64-dst-block, rel). Per block & relation: segment
// records staged into LDS, scanned by all threads via LDS broadcast; each
// (dstLocal, chunk) slice is OWNED by exactly one thread which accumulates
// pinv-scaled bf16 x-row gathers in registers, then writes its slice to the
// LDS A-tile (no atomics). A-tile -> MFMA A-fragments; all 8 relations +
// root accumulate into one AGPR accumulator. No per-relation H table.
//
// Output layout: direct permuted C-store, true-col pi(q)=(q%CT)*16+q/CT at
// short-position q. hmid inherits pi64 (W2/root2 k-rows pre-permuted), z
// inherits pi32 (decode dot invariant), bias folded in epilogue.
//
// Problem sizes fixed by harness: N=100000, E=1e6 uniform, NREL=8.
// 512-dst buckets: 196, ~5120 edges each (sigma~72); SCAP=+14sigma.
#define F_IN 64
#define F_HID 64
#define F_OUT 32
#define NREL 8
#define SCAP 6144    // staging capacity per 512-bucket (edges)
#define RCAP2 6528   // rec capacity per bucket (edges + 64 segs * 3 pad)
#define MAXBUCK 200
#define PA_PE 16     // edges per thread in binA

typedef __attribute__((ext_vector_type(8))) short bfrag;   // 8 bf16 (A/B frag)
typedef __attribute__((ext_vector_type(4))) float ffrag;   // 4 f32  (C/D frag)

// ---------------------------------------------------------------------------
// bf16 helpers (manual RNE pack)
__device__ inline unsigned short f2bf(float f) {
  unsigned u = __float_as_uint(f);
  unsigned r = (u + 0x7fffu + ((u >> 16) & 1u)) >> 16;
  return (unsigned short)r;
}
__device__ inline unsigned bf16pair(float lo, float hi) {
  return (unsigned)f2bf(lo) | ((unsigned)f2bf(hi) << 16);
}
__device__ inline float bflo(unsigned u) { return __uint_as_float(u << 16); }
__device__ inline float bfhi(unsigned u) { return __uint_as_float(u & 0xffff0000u); }
__device__ inline float dot8(uint4 a, uint4 b) {
  return bflo(a.x) * bflo(b.x) + bfhi(a.x) * bfhi(b.x) +
         bflo(a.y) * bflo(b.y) + bfhi(a.y) * bfhi(b.y) +
         bflo(a.z) * bflo(b.z) + bfhi(a.z) * bfhi(b.z) +
         bflo(a.w) * bflo(b.w) + bfhi(a.w) * bfhi(b.w);
}

// ---------------------------------------------------------------------------
// Fused prep: weight fragment swizzle for both layers (+root slots) + gcur.
// Fragment slot j at lane l holds Wsrc[kperm(k0+j)][c*16+(l&15)],
// k0 = s*32+(l>>4)*8. PERMK applies pi64 (layer 2: A operand is permuted).
template <int O, bool PERMK>
__device__ inline void wprep_one(int t, const float* __restrict__ W,
                                 const float* __restrict__ root,
                                 unsigned short* __restrict__ Wf) {
  constexpr int CT = O / 16;
  int l = t & 63;
  int s = (t >> 6) & 1;
  int rc = t >> 7;
  int c = rc % CT;
  int r = rc / CT;
  const float* wsrc = (r < NREL) ? W + (size_t)r * 64 * O : root;
  unsigned short* dst = Wf + (size_t)t * 8;
  int col = c * 16 + (l & 15);
  int k0 = s * 32 + ((l >> 4) * 8);
#pragma unroll
  for (int j = 0; j < 8; ++j) {
    int k = k0 + j;
    if (PERMK) k = (k & 3) * 16 + (k >> 2);   // pi64
    dst[j] = f2bf(wsrc[(size_t)k * O + col]);
  }
}

__global__ __launch_bounds__(256) void prep_kernel(
    const float* __restrict__ W1, const float* __restrict__ root1,
    const float* __restrict__ W2, const float* __restrict__ root2,
    unsigned short* __restrict__ wf1, unsigned short* __restrict__ wf2,
    int* __restrict__ gcur, int nbuck) {
  int gid = blockIdx.x * 256 + threadIdx.x;
  const int J1 = (NREL + 1) * (F_HID / 16) * 2 * 64;  // 4608
  const int J2 = (NREL + 1) * (F_OUT / 16) * 2 * 64;  // 2304
  if (gid < J1) {
    wprep_one<F_HID, false>(gid, W1, root1, wf1);
  } else if (gid < J1 + J2) {
    wprep_one<F_OUT, true>(gid - J1, W2, root2, wf2);
  } else if (gid - J1 - J2 < nbuck) {
    int b = gid - J1 - J2;
    gcur[b] = b * SCAP;
  }
}

// f32 -> bf16 conversion, 8 elements/thread
__global__ __launch_bounds__(256) void cvt_bf16_kernel(
    const float* __restrict__ in, unsigned* __restrict__ out, int n8) {
  int i = blockIdx.x * blockDim.x + threadIdx.x;
  if (i >= n8) return;
  const float4* p = (const float4*)(in + (size_t)i * 8);
  float4 a = p[0], b = p[1];
  uint4 o;
  o.x = bf16pair(a.x, a.y);
  o.y = bf16pair(a.z, a.w);
  o.z = bf16pair(b.x, b.y);
  o.w = bf16pair(b.z, b.w);
  *((uint4*)out + i) = o;
}

// ---------------------------------------------------------------------------
// Pass A: bin edges by 512-dst bucket into per-bucket staging regions.
// Pack: src (17b) | rel (3b, bit17) | dstLow9 (bit20).
__global__ __launch_bounds__(256) void binA_kernel(
    const int* __restrict__ src, const int* __restrict__ dst,
    const int* __restrict__ et, int* __restrict__ gcur,
    unsigned* __restrict__ staging, int E) {
  __shared__ int hist[MAXBUCK * 4];
  __shared__ int wbase[MAXBUCK * 4];
  const int tid = threadIdx.x;
  const int wave = tid >> 6;
  for (int i = tid; i < MAXBUCK * 4; i += 256) hist[i] = 0;
  __syncthreads();
  const int base = blockIdx.x * (256 * PA_PE);
  int dv[PA_PE], rk[PA_PE];
#pragma unroll
  for (int j = 0; j < PA_PE; ++j) {
    int e = base + j * 256 + tid;
    if (e < E) {
      int d = dst[e];
      dv[j] = d;
      rk[j] = atomicAdd(&hist[(d >> 9) * 4 + wave], 1);
    } else {
      dv[j] = -1;
    }
  }
  __syncthreads();
  for (int b = tid; b < MAXBUCK; b += 256) {
    int h0 = hist[b * 4 + 0], h1 = hist[b * 4 + 1];
    int h2 = hist[b * 4 + 2], h3 = hist[b * 4 + 3];
    int tot = h0 + h1 + h2 + h3;
    int gb = tot ? atomicAdd(&gcur[b], tot) : 0;
    wbase[b * 4 + 0] = gb;
    wbase[b * 4 + 1] = gb + h0;
    wbase[b * 4 + 2] = gb + h0 + h1;
    wbase[b * 4 + 3] = gb + h0 + h1 + h2;
  }
  __syncthreads();
#pragma unroll
  for (int j = 0; j < PA_PE; ++j) {
    if (dv[j] >= 0) {
      int e = base + j * 256 + tid;
      unsigned pk = (unsigned)src[e] | ((unsigned)et[e] << 17) |
                    ((unsigned)(dv[j] & 511) << 20);
      staging[wbase[(dv[j] >> 9) * 4 + wave] + rk[j]] = pk;
    }
  }
}

// Pass B: one block per 512-bucket. Per-(dstLocal,rel) counts in LDS
// (-> pinv); edges regrouped into 64 segments = (8 sub-blocks of 64 dsts) x
// (8 rels), each padded to a multiple of 4. Record: {src|dstLoc6<<17, pinv}.
__global__ __launch_bounds__(256) void binB_kernel(
    const unsigned* __restrict__ staging, const int* __restrict__ gcur,
    int2* __restrict__ rec, int* __restrict__ segS, int* __restrict__ segE,
    int N) {
  __shared__ int cnt8[512 * 8];   // counts, then reused as pinv (float bits)
  __shared__ int segp[64], segt[64], segEl[64], cur[64];
  const int b = blockIdx.x;
  const int tid = threadIdx.x;
  const int cnt_b = gcur[b] - b * SCAP;
  const unsigned* st = staging + (size_t)b * SCAP;
  for (int i = tid; i < 512 * 8; i += 256) cnt8[i] = 0;
  __syncthreads();
  for (int i = tid; i < cnt_b; i += 256) {
    unsigned e = st[i];
    atomicAdd(&cnt8[((e >> 20) & 511) * 8 + ((e >> 17) & 7)], 1);
  }
  __syncthreads();
  if (tid < 64) {           // seg (sb,r): tot = sum over 64 dsts
    int sb = tid >> 3, r = tid & 7;
    int tot = 0;
#pragma unroll 8
    for (int j = 0; j < 64; ++j) tot += cnt8[((sb << 6) + j) * 8 + r];
    segp[tid] = (tot + 3) & ~3;
  }
  __syncthreads();
  if (tid == 0) {           // exclusive scan of 64 padded totals
    int run = 0;
    for (int s = 0; s < 64; ++s) { segt[s] = run; run += segp[s]; }
  }
  __syncthreads();
  if (tid < 64) {
    int s0 = b * RCAP2 + segt[tid];
    int e0 = s0 + segp[tid];
    segS[b * 64 + tid] = s0;
    segE[b * 64 + tid] = e0;
    segEl[tid] = e0;
    cur[tid] = s0;
  }
  __syncthreads();
  for (int i = tid; i < 512 * 8; i += 256) {   // counts -> pinv (in place)
    int cc = cnt8[i];
    ((float*)cnt8)[i] = cc > 0 ? 1.0f / (float)cc : 0.0f;
  }
  __syncthreads();
  for (int i = tid; i < cnt_b; i += 256) {
    unsigned e = st[i];
    int s = e & 0x1FFFF;
    int r = (e >> 17) & 7;
    int dl = (e >> 20) & 511;
    int pos = atomicAdd(&cur[(dl >> 6) * 8 + r], 1);
    rec[pos] = make_int2(s | ((dl & 63) << 17), cnt8[dl * 8 + r]);
  }
  __syncthreads();
  if (tid < 64)
    for (int p = cur[tid]; p < segEl[tid]; ++p) rec[p] = make_int2(0, 0);
}

// ---------------------------------------------------------------------------
// Aggregate-first fused layer, ATOMIC-FREE: block = 64 dst nodes, 256 threads.
// Thread tid owns dst rows {tid>>3, 32+(tid>>3)} x feature chunk (tid&7).
// Per rel: stage segment records to LDS -> all threads scan via broadcast;
// owners gather pinv-scaled x rows into REGISTERS; one non-atomic LDS write
// of the owned slices; MFMA acc += A_r @ W_r. Root + bias (+ReLU) epilogue,
// direct permuted bf16 store.
template <int O, bool RELU>
__global__ __launch_bounds__(256) void ragg_kernel(
    const unsigned short* __restrict__ X,   // input table [.][64] bf16
    const unsigned short* __restrict__ Wf,  // 9 fragment slots
    const int* __restrict__ segS, const int* __restrict__ segE,
    const int2* __restrict__ rec, const float* __restrict__ bias,
    unsigned short* __restrict__ Y, int N) {
  constexpr int CT = O / 16;
  __shared__ float A[64][68];               // +4 pad
  __shared__ int2 recLds[256];
  const int tid = threadIdx.x;
  const int w = tid >> 6, l = tid & 63;
  const int blk = blockIdx.x;
  const int grp = tid >> 3;   // 0..31: owner of dls {grp, 32+grp}
  const int ch = tid & 7;     // feature chunk (8 bf16)
  ffrag acc[CT];
#pragma unroll
  for (int c = 0; c < CT; ++c) acc[c] = (ffrag){0.f, 0.f, 0.f, 0.f};
  for (int r = 0; r < NREL; ++r) {
    float fa[8] = {0.f, 0.f, 0.f, 0.f, 0.f, 0.f, 0.f, 0.f};
    float fb[8] = {0.f, 0.f, 0.f, 0.f, 0.f, 0.f, 0.f, 0.f};
    const int s0 = segS[blk * 8 + r];
    const int s1 = segE[blk * 8 + r];
    for (int base = s0; base < s1; base += 256) {
      const int cnt = min(256, s1 - base);
      __syncthreads();   // recLds reusable; prev-rel A-frag reads complete
      for (int i = tid; i < cnt; i += 256) recLds[i] = rec[base + i];
      __syncthreads();
      for (int p = 0; p < cnt; ++p) {
        int2 rcd = recLds[p];             // LDS broadcast
        int dl = (rcd.x >> 17) & 63;
        if ((dl & 31) == grp) {           // 8 owner threads respond
          float pv = __int_as_float(rcd.y);
          uint4 g = *(const uint4*)(X + (size_t)(rcd.x & 0x1FFFF) * 64 + ch * 8);
          if (dl >> 5) {
            fb[0] += pv * bflo(g.x); fb[1] += pv * bfhi(g.x);
            fb[2] += pv * bflo(g.y); fb[3] += pv * bfhi(g.y);
            fb[4] += pv * bflo(g.z); fb[5] += pv * bfhi(g.z);
            fb[6] += pv * bflo(g.w); fb[7] += pv * bfhi(g.w);
          } else {
            fa[0] += pv * bflo(g.x); fa[1] += pv * bfhi(g.x);
            fa[2] += pv * bflo(g.y); fa[3] += pv * bfhi(g.y);
            fa[4] += pv * bflo(g.z); fa[5] += pv * bfhi(g.z);
            fa[6] += pv * bflo(g.w); fa[7] += pv * bfhi(g.w);
          }
        }
      }
    }
    __syncthreads();   // scans done; prev-rel A-frag reads complete (empty-seg case)
#pragma unroll
    for (int j = 0; j < 8; ++j) A[grp][ch * 8 + j] = fa[j];
#pragma unroll
    for (int j = 0; j < 8; ++j) A[32 + grp][ch * 8 + j] = fb[j];
    __syncthreads();
    // A -> bf16 MFMA A-fragments (verified round-9 path)
    const float* ap = &A[w * 16 + (l & 15)][(l >> 4) * 8];
    float4 f0 = *(const float4*)(ap);
    float4 f1 = *(const float4*)(ap + 4);
    float4 f2 = *(const float4*)(ap + 32);
    float4 f3 = *(const float4*)(ap + 36);
    uint4 ua, ub;
    ua.x = bf16pair(f0.x, f0.y); ua.y = bf16pair(f0.z, f0.w);
    ua.z = bf16pair(f1.x, f1.y); ua.w = bf16pair(f1.z, f1.w);
    ub.x = bf16pair(f2.x, f2.y); ub.y = bf16pair(f2.z, f2.w);
    ub.z = bf16pair(f3.x, f3.y); ub.w = bf16pair(f3.z, f3.w);
    bfrag a0 = *(bfrag*)&ua, a1 = *(bfrag*)&ub;
    const unsigned short* wb = Wf + ((size_t)r * CT * 2 * 64 + l) * 8;
#pragma unroll
    for (int c = 0; c < CT; ++c) {
      bfrag b0 = *(const bfrag*)(wb + (size_t)(c * 2 + 0) * 512);
      bfrag b1 = *(const bfrag*)(wb + (size_t)(c * 2 + 1) * 512);
      acc[c] = __builtin_amdgcn_mfma_f32_16x16x32_bf16(a0, b0, acc[c], 0, 0, 0);
      acc[c] = __builtin_amdgcn_mfma_f32_16x16x32_bf16(a1, b1, acc[c], 0, 0, 0);
    }
  }
  // root term (slot 8): operand = own row of X
  int arow = blk * 64 + w * 16 + (l & 15);
  if (arow >= N) arow = N - 1;
  const unsigned short* xp = X + (size_t)arow * 64 + ((l >> 4) * 8);
  bfrag a0 = *(const bfrag*)(xp);
  bfrag a1 = *(const bfrag*)(xp + 32);
  const unsigned short* wb = Wf + ((size_t)NREL * CT * 2 * 64 + l) * 8;
#pragma unroll
  for (int c = 0; c < CT; ++c) {
    bfrag b0 = *(const bfrag*)(wb + (size_t)(c * 2 + 0) * 512);
    bfrag b1 = *(const bfrag*)(wb + (size_t)(c * 2 + 1) * 512);
    acc[c] = __builtin_amdgcn_mfma_f32_16x16x32_bf16(a0, b0, acc[c], 0, 0, 0);
    acc[c] = __builtin_amdgcn_mfma_f32_16x16x32_bf16(a1, b1, acc[c], 0, 0, 0);
  }
  // epilogue: bias (true col = c*16 + (l&15)), ReLU, permuted bf16 store
  float bv[CT];
#pragma unroll
  for (int c = 0; c < CT; ++c) bv[c] = bias[c * 16 + (l & 15)];
  const int rbase = blk * 64 + w * 16 + ((l >> 4) << 2);
#pragma unroll
  for (int i = 0; i < 4; ++i) {
    int row = rbase + i;
    if (row < N) {
      float v[CT];
#pragma unroll
      for (int c = 0; c < CT; ++c) {
        v[c] = acc[c][i] + bv[c];
        if (RELU) v[c] = fmaxf(v[c], 0.f);
      }
      if (O == 64) {
        uint2 o;
        o.x = bf16pair(v[0], v[1]);
        o.y = bf16pair(v[2], v[3]);
        *(uint2*)(Y + (size_t)row * 64 + (l & 15) * 4) = o;
      } else {
        *(unsigned*)(Y + (size_t)row * 32 + (l & 15) * 2) = bf16pair(v[0], v[1]);
      }
    }
  }
}

// ---------------------------------------------------------------------------
// Decode: out[e] = dot(z[src[e]], z[dst[e]]) over 32 bf16 features (pi32-
// permuted on both operands -> invariant).
__global__ __launch_bounds__(256) void decode_kernel(
    const unsigned* __restrict__ Z, const int* __restrict__ src,
    const int* __restrict__ dst, float* __restrict__ out, int E) {
  int e = blockIdx.x * blockDim.x + threadIdx.x;
  if (e >= E) return;
  const uint4* zs = (const uint4*)(Z + (size_t)src[e] * 16);
  const uint4* zd = (const uint4*)(Z + (size_t)dst[e] * 16);
  uint4 a0 = zs[0], a1 = zs[1], a2 = zs[2], a3 = zs[3];
  uint4 b0 = zd[0], b1 = zd[1], b2 = zd[2], b3 = zd[3];
  out[e] = dot8(a0, b0) + dot8(a1, b1) + dot8(a2, b2) + dot8(a3, b3);
}

// ---------------------------------------------------------------------------
extern "C" void kernel_launch(void* const* d_in, const int* in_sizes, int n_in,
                              void* d_out, int out_size, void* d_ws, size_t ws_size,
                              hipStream_t stream) {
  const float* x     = (const float*)d_in[0];
  const float* W1    = (const float*)d_in[1];
  const float* root1 = (const float*)d_in[2];
  const float* b1    = (const float*)d_in[3];
  const float* W2    = (const float*)d_in[4];
  const float* root2 = (const float*)d_in[5];
  const float* b2    = (const float*)d_in[6];
  const int*   ei    = (const int*)d_in[7];   // [2, E] int32
  const int*   et    = (const int*)d_in[8];   // [E] int32

  const int N = in_sizes[0] / F_IN;           // 100000
  const int E = in_sizes[8];                  // 1000000
  const int nbuck = (N + 511) >> 9;           // 196
  const int nblk64 = nbuck * 8;               // 1568 (64-dst blocks)
  const int* srcp = ei;
  const int* dstp = ei + E;

  // Workspace layout (bytes), peak ~47 MB
  char* ws = (char*)d_ws;
  int*            gcur    = (int*)(ws + 0);              //  800 B [nbuck]
  unsigned*       staging = (unsigned*)(ws + 4096);      //  4.9 MB [200*SCAP]
  int*            segS    = (int*)(ws + 4919296);        //  50 KB [nbuck*64]
  int*            segE    = (int*)(ws + 4969472);        //  50 KB
  int2*           rec     = (int2*)(ws + 5019648);       // 10.2 MB [nbuck*RCAP2]
  unsigned short* wf1     = (unsigned short*)(ws + 15255552);  // 73.7 KB (9 slots)
  unsigned short* wf2     = (unsigned short*)(ws + 15329280);  // 36.9 KB (9 slots)
  unsigned short* xb      = (unsigned short*)(ws + 15366144);  // 12.8 MB bf16[N*64]
  unsigned short* hmid    = (unsigned short*)(ws + 28166144);  // 12.8 MB bf16[N*64]
  unsigned short* z       = (unsigned short*)(ws + 40966144);  //  6.4 MB bf16[N*32]

  // ---- prep (wf1, wf2, gcur) + x->bf16 + bucketed 2-pass CSR build ----
  prep_kernel<<<28, 256, 0, stream>>>(W1, root1, W2, root2, wf1, wf2, gcur, nbuck);
  cvt_bf16_kernel<<<(N * (F_IN / 8) + 255) / 256, 256, 0, stream>>>(
      x, (unsigned*)xb, N * (F_IN / 8));
  binA_kernel<<<(E + 256 * PA_PE - 1) / (256 * PA_PE), 256, 0, stream>>>(
      srcp, dstp, et, gcur, staging, E);
  binB_kernel<<<nbuck, 256, 0, stream>>>(staging, gcur, rec, segS, segE, N);

  // ---- Layer 1: xb -> hmid (bf16, pi64) ----
  ragg_kernel<F_HID, true>
      <<<nblk64, 256, 0, stream>>>(xb, wf1, segS, segE, rec, b1, hmid, N);

  // ---- Layer 2: hmid -> z (bf16, pi32) ----
  ragg_kernel<F_OUT, false>
      <<<nblk64, 256, 0, stream>>>(hmid, wf2, segS, segE, rec, b2, z, N);

  // ---- Decode ----
  decode_kernel<<<(E + 255) / 256, 256, 0, stream>>>((const unsigned*)z, srcp, dstp,
                                                     (float*)d_out, E);
}

// Round 11
// 225.284 us; speedup vs baseline: 3.8136x; 2.1055x over previous
//
#include <hip/hip_runtime.h>

// RGCN link predictor, aggregate-first formulation with direct per-list
// iteration (no scan, no atomics, no pinv):
//   out[i] = sum_r W_r @ mean_{j in N_r(i)} x_j + root@x_i + b
// binB sorts each 512-dst bucket's edges into 4096 exact (subblock, rel,
// dstLocal) lists. In ragg, the 8-thread group owning dstLocal dl iterates
// only its own lists: rec[p] (4B src) -> coalesced 128B X-row gather ->
// register sum; mean = sum * 1/len; slice written to LDS A-tile; MFMA
// accumulates all 8 relations + root into one AGPR accumulator.
//
// Output layout: direct permuted C-store, true-col pi(q)=(q%CT)*16+q/CT at
// short-position q. hmid inherits pi64 (W2/root2 k-rows pre-permuted), z
// inherits pi32 (decode dot invariant), bias folded in epilogue.
//
// Problem sizes fixed by harness: N=100000, E=1e6 uniform, NREL=8.
// 512-dst buckets: 196, ~5120 edges each (sigma~72); SCAP=+14sigma.
#define F_IN 64
#define F_HID 64
#define F_OUT 32
#define NREL 8
#define SCAP 6144    // staging/rec capacity per 512-bucket (edges)
#define MAXBUCK 200
#define PA_PE 16     // edges per thread in binA

typedef __attribute__((ext_vector_type(8))) short bfrag;   // 8 bf16 (A/B frag)
typedef __attribute__((ext_vector_type(4))) float ffrag;   // 4 f32  (C/D frag)

// ---------------------------------------------------------------------------
// bf16 helpers (manual RNE pack)
__device__ inline unsigned short f2bf(float f) {
  unsigned u = __float_as_uint(f);
  unsigned r = (u + 0x7fffu + ((u >> 16) & 1u)) >> 16;
  return (unsigned short)r;
}
__device__ inline unsigned bf16pair(float lo, float hi) {
  return (unsigned)f2bf(lo) | ((unsigned)f2bf(hi) << 16);
}
__device__ inline float bflo(unsigned u) { return __uint_as_float(u << 16); }
__device__ inline float bfhi(unsigned u) { return __uint_as_float(u & 0xffff0000u); }
__device__ inline float dot8(uint4 a, uint4 b) {
  return bflo(a.x) * bflo(b.x) + bfhi(a.x) * bfhi(b.x) +
         bflo(a.y) * bflo(b.y) + bfhi(a.y) * bfhi(b.y) +
         bflo(a.z) * bflo(b.z) + bfhi(a.z) * bfhi(b.z) +
         bflo(a.w) * bflo(b.w) + bfhi(a.w) * bfhi(b.w);
}

// ---------------------------------------------------------------------------
// Fused prep: weight fragment swizzle for both layers (+root slots) + gcur.
// Fragment slot j at lane l holds Wsrc[kperm(k0+j)][c*16+(l&15)],
// k0 = s*32+(l>>4)*8. PERMK applies pi64 (layer 2: A operand is permuted).
template <int O, bool PERMK>
__device__ inline void wprep_one(int t, const float* __restrict__ W,
                                 const float* __restrict__ root,
                                 unsigned short* __restrict__ Wf) {
  constexpr int CT = O / 16;
  int l = t & 63;
  int s = (t >> 6) & 1;
  int rc = t >> 7;
  int c = rc % CT;
  int r = rc / CT;
  const float* wsrc = (r < NREL) ? W + (size_t)r * 64 * O : root;
  unsigned short* dst = Wf + (size_t)t * 8;
  int col = c * 16 + (l & 15);
  int k0 = s * 32 + ((l >> 4) * 8);
#pragma unroll
  for (int j = 0; j < 8; ++j) {
    int k = k0 + j;
    if (PERMK) k = (k & 3) * 16 + (k >> 2);   // pi64
    dst[j] = f2bf(wsrc[(size_t)k * O + col]);
  }
}

__global__ __launch_bounds__(256) void prep_kernel(
    const float* __restrict__ W1, const float* __restrict__ root1,
    const float* __restrict__ W2, const float* __restrict__ root2,
    unsigned short* __restrict__ wf1, unsigned short* __restrict__ wf2,
    int* __restrict__ gcur, int nbuck) {
  int gid = blockIdx.x * 256 + threadIdx.x;
  const int J1 = (NREL + 1) * (F_HID / 16) * 2 * 64;  // 4608
  const int J2 = (NREL + 1) * (F_OUT / 16) * 2 * 64;  // 2304
  if (gid < J1) {
    wprep_one<F_HID, false>(gid, W1, root1, wf1);
  } else if (gid < J1 + J2) {
    wprep_one<F_OUT, true>(gid - J1, W2, root2, wf2);
  } else if (gid - J1 - J2 < nbuck) {
    int b = gid - J1 - J2;
    gcur[b] = b * SCAP;
  }
}

// f32 -> bf16 conversion, 8 elements/thread
__global__ __launch_bounds__(256) void cvt_bf16_kernel(
    const float* __restrict__ in, unsigned* __restrict__ out, int n8) {
  int i = blockIdx.x * blockDim.x + threadIdx.x;
  if (i >= n8) return;
  const float4* p = (const float4*)(in + (size_t)i * 8);
  float4 a = p[0], b = p[1];
  uint4 o;
  o.x = bf16pair(a.x, a.y);
  o.y = bf16pair(a.z, a.w);
  o.z = bf16pair(b.x, b.y);
  o.w = bf16pair(b.z, b.w);
  *((uint4*)out + i) = o;
}

// ---------------------------------------------------------------------------
// Pass A: bin edges by 512-dst bucket into per-bucket staging regions.
// Pack: src (17b) | rel (3b, bit17) | dstLow9 (bit20).
__global__ __launch_bounds__(256) void binA_kernel(
    const int* __restrict__ src, const int* __restrict__ dst,
    const int* __restrict__ et, int* __restrict__ gcur,
    unsigned* __restrict__ staging, int E) {
  __shared__ int hist[MAXBUCK * 4];
  __shared__ int wbase[MAXBUCK * 4];
  const int tid = threadIdx.x;
  const int wave = tid >> 6;
  for (int i = tid; i < MAXBUCK * 4; i += 256) hist[i] = 0;
  __syncthreads();
  const int base = blockIdx.x * (256 * PA_PE);
  int dv[PA_PE], rk[PA_PE];
#pragma unroll
  for (int j = 0; j < PA_PE; ++j) {
    int e = base + j * 256 + tid;
    if (e < E) {
      int d = dst[e];
      dv[j] = d;
      rk[j] = atomicAdd(&hist[(d >> 9) * 4 + wave], 1);
    } else {
      dv[j] = -1;
    }
  }
  __syncthreads();
  for (int b = tid; b < MAXBUCK; b += 256) {
    int h0 = hist[b * 4 + 0], h1 = hist[b * 4 + 1];
    int h2 = hist[b * 4 + 2], h3 = hist[b * 4 + 3];
    int tot = h0 + h1 + h2 + h3;
    int gb = tot ? atomicAdd(&gcur[b], tot) : 0;
    wbase[b * 4 + 0] = gb;
    wbase[b * 4 + 1] = gb + h0;
    wbase[b * 4 + 2] = gb + h0 + h1;
    wbase[b * 4 + 3] = gb + h0 + h1 + h2;
  }
  __syncthreads();
#pragma unroll
  for (int j = 0; j < PA_PE; ++j) {
    if (dv[j] >= 0) {
      int e = base + j * 256 + tid;
      unsigned pk = (unsigned)src[e] | ((unsigned)et[e] << 17) |
                    ((unsigned)(dv[j] & 511) << 20);
      staging[wbase[(dv[j] >> 9) * 4 + wave] + rk[j]] = pk;
    }
  }
}

// Pass B: one block per 512-bucket. Histogram the 4096 (sb,rel,dl6) lists,
// block-scan the counts -> exact starts (absolute, base b*SCAP), place 4B
// src records. startsD has 4097 entries per bucket (last = bucket end).
__global__ __launch_bounds__(256) void binB_kernel(
    const unsigned* __restrict__ staging, const int* __restrict__ gcur,
    int* __restrict__ recI, int* __restrict__ startsD) {
  __shared__ int cnt[4096];
  __shared__ int cur[4096];
  __shared__ int tsum[256];
  const int b = blockIdx.x;
  const int tid = threadIdx.x;
  const int cnt_b = gcur[b] - b * SCAP;
  const unsigned* st = staging + (size_t)b * SCAP;
  for (int i = tid; i < 4096; i += 256) cnt[i] = 0;
  __syncthreads();
  for (int i = tid; i < cnt_b; i += 256) {
    unsigned e = st[i];
    int dl = (e >> 20) & 511;
    int idx = ((dl >> 6) << 9) | (((e >> 17) & 7) << 6) | (dl & 63);
    atomicAdd(&cnt[idx], 1);
  }
  __syncthreads();
  int loc[16];
  int tot = 0;
#pragma unroll
  for (int j = 0; j < 16; ++j) { loc[j] = cnt[tid * 16 + j]; tot += loc[j]; }
  tsum[tid] = tot;
  __syncthreads();
  for (int off = 1; off < 256; off <<= 1) {
    int v = (tid >= off) ? tsum[tid - off] : 0;
    __syncthreads();
    tsum[tid] += v;
    __syncthreads();
  }
  int run = b * SCAP + tsum[tid] - tot;   // exclusive prefix, absolute
#pragma unroll
  for (int j = 0; j < 16; ++j) {
    startsD[b * 4097 + tid * 16 + j] = run;
    cur[tid * 16 + j] = run;
    run += loc[j];
  }
  if (tid == 0) startsD[b * 4097 + 4096] = gcur[b];
  __syncthreads();
  for (int i = tid; i < cnt_b; i += 256) {
    unsigned e = st[i];
    int dl = (e >> 20) & 511;
    int idx = ((dl >> 6) << 9) | (((e >> 17) & 7) << 6) | (dl & 63);
    int pos = atomicAdd(&cur[idx], 1);
    recI[pos] = e & 0x1FFFF;
  }
}

// ---------------------------------------------------------------------------
// Aggregate-first fused layer, direct-iteration: block = 64 dst nodes,
// 256 threads. Thread tid (group grp=tid>>3, chunk ch=tid&7) owns dst rows
// {grp, 32+grp}. Per rel: group iterates its two exact lists (rec = 4B src),
// gathering coalesced 128B X rows and summing in registers; mean = sum/len;
// one non-atomic LDS A-tile write; MFMA acc += A_r @ W_r. Root + bias
// (+ReLU) epilogue, direct permuted bf16 store.
template <int O, bool RELU>
__global__ __launch_bounds__(256) void ragg_kernel(
    const unsigned short* __restrict__ X,   // input table [.][64] bf16
    const unsigned short* __restrict__ Wf,  // 9 fragment slots
    const int* __restrict__ startsD, const int* __restrict__ recI,
    const float* __restrict__ bias, unsigned short* __restrict__ Y, int N) {
  constexpr int CT = O / 16;
  __shared__ float A[64][68];               // +4 pad
  const int tid = threadIdx.x;
  const int w = tid >> 6, l = tid & 63;
  const int blk = blockIdx.x;
  const int b = blk >> 3, sb = blk & 7;
  const int grp = tid >> 3;   // 0..31: owner of dls {grp, 32+grp}
  const int ch = tid & 7;     // feature chunk (8 bf16)
  ffrag acc[CT];
#pragma unroll
  for (int c = 0; c < CT; ++c) acc[c] = (ffrag){0.f, 0.f, 0.f, 0.f};
  for (int r = 0; r < NREL; ++r) {
    const int base = b * 4097 + (sb << 9) + (r << 6);
    const int sA = startsD[base + grp];
    const int eA = startsD[base + grp + 1];
    const int sB = startsD[base + 32 + grp];
    const int eB = startsD[base + 32 + grp + 1];
    float fa[8] = {0.f, 0.f, 0.f, 0.f, 0.f, 0.f, 0.f, 0.f};
    float fb[8] = {0.f, 0.f, 0.f, 0.f, 0.f, 0.f, 0.f, 0.f};
    for (int p = sA; p < eA; ++p) {
      uint4 g = *(const uint4*)(X + (size_t)recI[p] * 64 + ch * 8);
      fa[0] += bflo(g.x); fa[1] += bfhi(g.x);
      fa[2] += bflo(g.y); fa[3] += bfhi(g.y);
      fa[4] += bflo(g.z); fa[5] += bfhi(g.z);
      fa[6] += bflo(g.w); fa[7] += bfhi(g.w);
    }
    for (int p = sB; p < eB; ++p) {
      uint4 g = *(const uint4*)(X + (size_t)recI[p] * 64 + ch * 8);
      fb[0] += bflo(g.x); fb[1] += bfhi(g.x);
      fb[2] += bflo(g.y); fb[3] += bfhi(g.y);
      fb[4] += bflo(g.z); fb[5] += bfhi(g.z);
      fb[6] += bflo(g.w); fb[7] += bfhi(g.w);
    }
    const float invA = (eA > sA) ? 1.f / (float)(eA - sA) : 0.f;
    const float invB = (eB > sB) ? 1.f / (float)(eB - sB) : 0.f;
    __syncthreads();   // prev rel's A-frag reads complete before overwrite
#pragma unroll
    for (int j = 0; j < 8; ++j) A[grp][ch * 8 + j] = fa[j] * invA;
#pragma unroll
    for (int j = 0; j < 8; ++j) A[32 + grp][ch * 8 + j] = fb[j] * invB;
    __syncthreads();
    // A -> bf16 MFMA A-fragments (verified round-9/10 path)
    const float* ap = &A[w * 16 + (l & 15)][(l >> 4) * 8];
    float4 f0 = *(const float4*)(ap);
    float4 f1 = *(const float4*)(ap + 4);
    float4 f2 = *(const float4*)(ap + 32);
    float4 f3 = *(const float4*)(ap + 36);
    uint4 ua, ub;
    ua.x = bf16pair(f0.x, f0.y); ua.y = bf16pair(f0.z, f0.w);
    ua.z = bf16pair(f1.x, f1.y); ua.w = bf16pair(f1.z, f1.w);
    ub.x = bf16pair(f2.x, f2.y); ub.y = bf16pair(f2.z, f2.w);
    ub.z = bf16pair(f3.x, f3.y); ub.w = bf16pair(f3.z, f3.w);
    bfrag a0 = *(bfrag*)&ua, a1 = *(bfrag*)&ub;
    const unsigned short* wb = Wf + ((size_t)r * CT * 2 * 64 + l) * 8;
#pragma unroll
    for (int c = 0; c < CT; ++c) {
      bfrag b0 = *(const bfrag*)(wb + (size_t)(c * 2 + 0) * 512);
      bfrag b1 = *(const bfrag*)(wb + (size_t)(c * 2 + 1) * 512);
      acc[c] = __builtin_amdgcn_mfma_f32_16x16x32_bf16(a0, b0, acc[c], 0, 0, 0);
      acc[c] = __builtin_amdgcn_mfma_f32_16x16x32_bf16(a1, b1, acc[c], 0, 0, 0);
    }
  }
  // root term (slot 8): operand = own row of X
  int arow = blk * 64 + w * 16 + (l & 15);
  if (arow >= N) arow = N - 1;
  const unsigned short* xp = X + (size_t)arow * 64 + ((l >> 4) * 8);
  bfrag a0 = *(const bfrag*)(xp);
  bfrag a1 = *(const bfrag*)(xp + 32);
  const unsigned short* wb = Wf + ((size_t)NREL * CT * 2 * 64 + l) * 8;
#pragma unroll
  for (int c = 0; c < CT; ++c) {
    bfrag b0 = *(const bfrag*)(wb + (size_t)(c * 2 + 0) * 512);
    bfrag b1 = *(const bfrag*)(wb + (size_t)(c * 2 + 1) * 512);
    acc[c] = __builtin_amdgcn_mfma_f32_16x16x32_bf16(a0, b0, acc[c], 0, 0, 0);
    acc[c] = __builtin_amdgcn_mfma_f32_16x16x32_bf16(a1, b1, acc[c], 0, 0, 0);
  }
  // epilogue: bias (true col = c*16 + (l&15)), ReLU, permuted bf16 store
  float bv[CT];
#pragma unroll
  for (int c = 0; c < CT; ++c) bv[c] = bias[c * 16 + (l & 15)];
  const int rbase = blk * 64 + w * 16 + ((l >> 4) << 2);
#pragma unroll
  for (int i = 0; i < 4; ++i) {
    int row = rbase + i;
    if (row < N) {
      float v[CT];
#pragma unroll
      for (int c = 0; c < CT; ++c) {
        v[c] = acc[c][i] + bv[c];
        if (RELU) v[c] = fmaxf(v[c], 0.f);
      }
      if (O == 64) {
        uint2 o;
        o.x = bf16pair(v[0], v[1]);
        o.y = bf16pair(v[2], v[3]);
        *(uint2*)(Y + (size_t)row * 64 + (l & 15) * 4) = o;
      } else {
        *(unsigned*)(Y + (size_t)row * 32 + (l & 15) * 2) = bf16pair(v[0], v[1]);
      }
    }
  }
}

// ---------------------------------------------------------------------------
// Decode: out[e] = dot(z[src[e]], z[dst[e]]) over 32 bf16 features (pi32-
// permuted on both operands -> invariant).
__global__ __launch_bounds__(256) void decode_kernel(
    const unsigned* __restrict__ Z, const int* __restrict__ src,
    const int* __restrict__ dst, float* __restrict__ out, int E) {
  int e = blockIdx.x * blockDim.x + threadIdx.x;
  if (e >= E) return;
  const uint4* zs = (const uint4*)(Z + (size_t)src[e] * 16);
  const uint4* zd = (const uint4*)(Z + (size_t)dst[e] * 16);
  uint4 a0 = zs[0], a1 = zs[1], a2 = zs[2], a3 = zs[3];
  uint4 b0 = zd[0], b1 = zd[1], b2 = zd[2], b3 = zd[3];
  out[e] = dot8(a0, b0) + dot8(a1, b1) + dot8(a2, b2) + dot8(a3, b3);
}

// ---------------------------------------------------------------------------
extern "C" void kernel_launch(void* const* d_in, const int* in_sizes, int n_in,
                              void* d_out, int out_size, void* d_ws, size_t ws_size,
                              hipStream_t stream) {
  const float* x     = (const float*)d_in[0];
  const float* W1    = (const float*)d_in[1];
  const float* root1 = (const float*)d_in[2];
  const float* b1    = (const float*)d_in[3];
  const float* W2    = (const float*)d_in[4];
  const float* root2 = (const float*)d_in[5];
  const float* b2    = (const float*)d_in[6];
  const int*   ei    = (const int*)d_in[7];   // [2, E] int32
  const int*   et    = (const int*)d_in[8];   // [E] int32

  const int N = in_sizes[0] / F_IN;           // 100000
  const int E = in_sizes[8];                  // 1000000
  const int nbuck = (N + 511) >> 9;           // 196
  const int nblk64 = nbuck * 8;               // 1568 (64-dst blocks)
  const int* srcp = ei;
  const int* dstp = ei + E;

  // Workspace layout (bytes), peak ~45 MB
  char* ws = (char*)d_ws;
  int*            gcur    = (int*)(ws + 0);              //  800 B [nbuck]
  unsigned*       staging = (unsigned*)(ws + 4096);      //  4.9 MB [200*SCAP]
  int*            startsD = (int*)(ws + 4919296);        //  3.2 MB [nbuck*4097]
  int*            recI    = (int*)(ws + 8131584);        //  4.9 MB [200*SCAP]
  unsigned short* wf1     = (unsigned short*)(ws + 13046784);  // 73.7 KB (9 slots)
  unsigned short* wf2     = (unsigned short*)(ws + 13120512);  // 36.9 KB (9 slots)
  unsigned short* xb      = (unsigned short*)(ws + 13157376);  // 12.8 MB bf16[N*64]
  unsigned short* hmid    = (unsigned short*)(ws + 25957376);  // 12.8 MB bf16[N*64]
  unsigned short* z       = (unsigned short*)(ws + 38757376);  //  6.4 MB bf16[N*32]

  // ---- prep (wf1, wf2, gcur) + x->bf16 + bucketed 2-pass CSR build ----
  prep_kernel<<<28, 256, 0, stream>>>(W1, root1, W2, root2, wf1, wf2, gcur, nbuck);
  cvt_bf16_kernel<<<(N * (F_IN / 8) + 255) / 256, 256, 0, stream>>>(
      x, (unsigned*)xb, N * (F_IN / 8));
  binA_kernel<<<(E + 256 * PA_PE - 1) / (256 * PA_PE), 256, 0, stream>>>(
      srcp, dstp, et, gcur, staging, E);
  binB_kernel<<<nbuck, 256, 0, stream>>>(staging, gcur, recI, startsD);

  // ---- Layer 1: xb -> hmid (bf16, pi64) ----
  ragg_kernel<F_HID, true>
      <<<nblk64, 256, 0, stream>>>(xb, wf1, startsD, recI, b1, hmid, N);

  // ---- Layer 2: hmid -> z (bf16, pi32) ----
  ragg_kernel<F_OUT, false>
      <<<nblk64, 256, 0, stream>>>(hmid, wf2, startsD, recI, b2, z, N);

  // ---- Decode ----
  decode_kernel<<<(E + 255) / 256, 256, 0, stream>>>((const unsigned*)z, srcp, dstp,
                                                     (float*)d_out, E);
}

// Round 12
// 193.629 us; speedup vs baseline: 4.4370x; 1.1635x over previous
//
#include <hip/hip_runtime.h>

// RGCN link predictor, aggregate-first with MFMA-based mean aggregation:
//   out[i] = sum_r W_r @ mean_{j in N_r(i)} x_j + root@x_i + b
// Per (64-dst block, rel), in chunks of 32 edges:
//   Xg[32][64] <- coalesced gathers of source rows (LDS, B-operand layout)
//   S[64][32]  <- one-hot selection matrix carrying bf16 pinv (A-operand)
//   aggD += S @ Xg   (4 MFMAs; K=32)  -> per-rel mean tile in registers
// Then A-tile LDS round-trip -> verified W-mult path: acc += A_r @ W_r for
// all 8 rels + root into one AGPR accumulator. No H table, no atomics, no
// serial list walks: 256 independent gathers in flight per chunk.
//
// Output layout: direct permuted C-store, true-col pi(q)=(q%CT)*16+q/CT at
// short-position q. hmid inherits pi64 (W2/root2 k-rows pre-permuted), z
// inherits pi32 (decode dot invariant), bias folded in epilogue.
//
// Problem sizes fixed by harness: N=100000, E=1e6 uniform, NREL=8.
// 512-dst buckets: 196, ~5120 edges each (sigma~72); SCAP=+14sigma.
#define F_IN 64
#define F_HID 64
#define F_OUT 32
#define NREL 8
#define SCAP 6144    // staging/rec capacity per 512-bucket (edges)
#define MAXBUCK 200
#define PA_PE 16     // edges per thread in binA

typedef __attribute__((ext_vector_type(8))) short bfrag;   // 8 bf16 (A/B frag)
typedef __attribute__((ext_vector_type(4))) float ffrag;   // 4 f32  (C/D frag)

// ---------------------------------------------------------------------------
// bf16 helpers (manual RNE pack)
__device__ inline unsigned short f2bf(float f) {
  unsigned u = __float_as_uint(f);
  unsigned r = (u + 0x7fffu + ((u >> 16) & 1u)) >> 16;
  return (unsigned short)r;
}
__device__ inline unsigned bf16pair(float lo, float hi) {
  return (unsigned)f2bf(lo) | ((unsigned)f2bf(hi) << 16);
}
__device__ inline float bflo(unsigned u) { return __uint_as_float(u << 16); }
__device__ inline float bfhi(unsigned u) { return __uint_as_float(u & 0xffff0000u); }
__device__ inline float dot8(uint4 a, uint4 b) {
  return bflo(a.x) * bflo(b.x) + bfhi(a.x) * bfhi(b.x) +
         bflo(a.y) * bflo(b.y) + bfhi(a.y) * bfhi(b.y) +
         bflo(a.z) * bflo(b.z) + bfhi(a.z) * bfhi(b.z) +
         bflo(a.w) * bflo(b.w) + bfhi(a.w) * bfhi(b.w);
}

// ---------------------------------------------------------------------------
// Fused prep: weight fragment swizzle for both layers (+root slots) + gcur.
// Fragment slot j at lane l holds Wsrc[kperm(k0+j)][c*16+(l&15)],
// k0 = s*32+(l>>4)*8. PERMK applies pi64 (layer 2: A operand is permuted).
template <int O, bool PERMK>
__device__ inline void wprep_one(int t, const float* __restrict__ W,
                                 const float* __restrict__ root,
                                 unsigned short* __restrict__ Wf) {
  constexpr int CT = O / 16;
  int l = t & 63;
  int s = (t >> 6) & 1;
  int rc = t >> 7;
  int c = rc % CT;
  int r = rc / CT;
  const float* wsrc = (r < NREL) ? W + (size_t)r * 64 * O : root;
  unsigned short* dst = Wf + (size_t)t * 8;
  int col = c * 16 + (l & 15);
  int k0 = s * 32 + ((l >> 4) * 8);
#pragma unroll
  for (int j = 0; j < 8; ++j) {
    int k = k0 + j;
    if (PERMK) k = (k & 3) * 16 + (k >> 2);   // pi64
    dst[j] = f2bf(wsrc[(size_t)k * O + col]);
  }
}

__global__ __launch_bounds__(256) void prep_kernel(
    const float* __restrict__ W1, const float* __restrict__ root1,
    const float* __restrict__ W2, const float* __restrict__ root2,
    unsigned short* __restrict__ wf1, unsigned short* __restrict__ wf2,
    int* __restrict__ gcur, int nbuck) {
  int gid = blockIdx.x * 256 + threadIdx.x;
  const int J1 = (NREL + 1) * (F_HID / 16) * 2 * 64;  // 4608
  const int J2 = (NREL + 1) * (F_OUT / 16) * 2 * 64;  // 2304
  if (gid < J1) {
    wprep_one<F_HID, false>(gid, W1, root1, wf1);
  } else if (gid < J1 + J2) {
    wprep_one<F_OUT, true>(gid - J1, W2, root2, wf2);
  } else if (gid - J1 - J2 < nbuck) {
    int b = gid - J1 - J2;
    gcur[b] = b * SCAP;
  }
}

// f32 -> bf16 conversion, 8 elements/thread
__global__ __launch_bounds__(256) void cvt_bf16_kernel(
    const float* __restrict__ in, unsigned* __restrict__ out, int n8) {
  int i = blockIdx.x * blockDim.x + threadIdx.x;
  if (i >= n8) return;
  const float4* p = (const float4*)(in + (size_t)i * 8);
  float4 a = p[0], b = p[1];
  uint4 o;
  o.x = bf16pair(a.x, a.y);
  o.y = bf16pair(a.z, a.w);
  o.z = bf16pair(b.x, b.y);
  o.w = bf16pair(b.z, b.w);
  *((uint4*)out + i) = o;
}

// ---------------------------------------------------------------------------
// Pass A: bin edges by 512-dst bucket into per-bucket staging regions.
// Pack: src (17b) | rel (3b, bit17) | dstLow9 (bit20).
__global__ __launch_bounds__(256) void binA_kernel(
    const int* __restrict__ src, const int* __restrict__ dst,
    const int* __restrict__ et, int* __restrict__ gcur,
    unsigned* __restrict__ staging, int E) {
  __shared__ int hist[MAXBUCK * 4];
  __shared__ int wbase[MAXBUCK * 4];
  const int tid = threadIdx.x;
  const int wave = tid >> 6;
  for (int i = tid; i < MAXBUCK * 4; i += 256) hist[i] = 0;
  __syncthreads();
  const int base = blockIdx.x * (256 * PA_PE);
  int dv[PA_PE], rk[PA_PE];
#pragma unroll
  for (int j = 0; j < PA_PE; ++j) {
    int e = base + j * 256 + tid;
    if (e < E) {
      int d = dst[e];
      dv[j] = d;
      rk[j] = atomicAdd(&hist[(d >> 9) * 4 + wave], 1);
    } else {
      dv[j] = -1;
    }
  }
  __syncthreads();
  for (int b = tid; b < MAXBUCK; b += 256) {
    int h0 = hist[b * 4 + 0], h1 = hist[b * 4 + 1];
    int h2 = hist[b * 4 + 2], h3 = hist[b * 4 + 3];
    int tot = h0 + h1 + h2 + h3;
    int gb = tot ? atomicAdd(&gcur[b], tot) : 0;
    wbase[b * 4 + 0] = gb;
    wbase[b * 4 + 1] = gb + h0;
    wbase[b * 4 + 2] = gb + h0 + h1;
    wbase[b * 4 + 3] = gb + h0 + h1 + h2;
  }
  __syncthreads();
#pragma unroll
  for (int j = 0; j < PA_PE; ++j) {
    if (dv[j] >= 0) {
      int e = base + j * 256 + tid;
      unsigned pk = (unsigned)src[e] | ((unsigned)et[e] << 17) |
                    ((unsigned)(dv[j] & 511) << 20);
      staging[wbase[(dv[j] >> 9) * 4 + wave] + rk[j]] = pk;
    }
  }
}

// Pass B: one block per 512-bucket. Histogram the 4096 (sb,rel,dl6) lists,
// block-scan the counts -> exact starts (absolute, base b*SCAP), place 4B
// records {src | dl6<<17}. startsD has 4097 entries/bucket (last = end).
__global__ __launch_bounds__(256) void binB_kernel(
    const unsigned* __restrict__ staging, const int* __restrict__ gcur,
    int* __restrict__ recI, int* __restrict__ startsD) {
  __shared__ int cnt[4096];
  __shared__ int cur[4096];
  __shared__ int tsum[256];
  const int b = blockIdx.x;
  const int tid = threadIdx.x;
  const int cnt_b = gcur[b] - b * SCAP;
  const unsigned* st = staging + (size_t)b * SCAP;
  for (int i = tid; i < 4096; i += 256) cnt[i] = 0;
  __syncthreads();
  for (int i = tid; i < cnt_b; i += 256) {
    unsigned e = st[i];
    int dl = (e >> 20) & 511;
    int idx = ((dl >> 6) << 9) | (((e >> 17) & 7) << 6) | (dl & 63);
    atomicAdd(&cnt[idx], 1);
  }
  __syncthreads();
  int loc[16];
  int tot = 0;
#pragma unroll
  for (int j = 0; j < 16; ++j) { loc[j] = cnt[tid * 16 + j]; tot += loc[j]; }
  tsum[tid] = tot;
  __syncthreads();
  for (int off = 1; off < 256; off <<= 1) {
    int v = (tid >= off) ? tsum[tid - off] : 0;
    __syncthreads();
    tsum[tid] += v;
    __syncthreads();
  }
  int run = b * SCAP + tsum[tid] - tot;   // exclusive prefix, absolute
#pragma unroll
  for (int j = 0; j < 16; ++j) {
    startsD[b * 4097 + tid * 16 + j] = run;
    cur[tid * 16 + j] = run;
    run += loc[j];
  }
  if (tid == 0) startsD[b * 4097 + 4096] = gcur[b];
  __syncthreads();
  for (int i = tid; i < cnt_b; i += 256) {
    unsigned e = st[i];
    int dl = (e >> 20) & 511;
    int idx = ((dl >> 6) << 9) | (((e >> 17) & 7) << 6) | (dl & 63);
    int pos = atomicAdd(&cur[idx], 1);
    recI[pos] = (int)(e & 0x1FFFF) | ((dl & 63) << 17);
  }
}

// ---------------------------------------------------------------------------
// Aggregate-first fused layer with MFMA aggregation. Block = 64 dst nodes,
// 256 threads (4 waves). Per rel, per 32-edge chunk: thread (ec=tid>>3,
// ch=tid&7) gathers 16B of edge ec's X row into Xg (B-operand layout);
// column-owner thread maintains one-hot S (A-operand, bf16 pinv, self-
// cleaning). aggD += S@Xg (4 MFMA, wave = n-tile). Per rel: aggD -> bf16
// A-tile in LDS -> verified A@W_r MFMA accumulate (wave = m-tile). Root +
// bias (+ReLU) epilogue with direct permuted bf16 store.
template <int O, bool RELU>
__global__ __launch_bounds__(256) void ragg_kernel(
    const unsigned short* __restrict__ X,   // input table [.][64] bf16
    const unsigned short* __restrict__ Wf,  // 9 fragment slots
    const int* __restrict__ startsD, const int* __restrict__ recI,
    const float* __restrict__ bias, unsigned short* __restrict__ Y, int N) {
  constexpr int CT = O / 16;
  __shared__ unsigned short S[64 * 40];     // A-operand: S[dl][edge], pad 40
  __shared__ unsigned short Xg[32 * 68];    // B-operand: Xg[edge][feat], pad 68
  __shared__ unsigned short A[64 * 72];     // mean tile A[dst][feat], pad 72
  __shared__ float pinvL[64];
  const int tid = threadIdx.x;
  const int w = tid >> 6, l = tid & 63;
  const int blk = blockIdx.x;
  const int b = blk >> 3, sb = blk & 7;
  const int ec = tid >> 3;    // edge slot 0..31
  const int ch = tid & 7;     // feature chunk (8 bf16)
  const int cl = l & 15, kgb = (l >> 4) << 3;
  int prev_dl = -1;
  // one-time zero (avoid NaN garbage under zero S columns)
  for (int i = tid; i < 64 * 40 / 2; i += 256) ((unsigned*)S)[i] = 0u;
  for (int i = tid; i < 32 * 68 / 2; i += 256) ((unsigned*)Xg)[i] = 0u;
  ffrag acc[CT];
#pragma unroll
  for (int c = 0; c < CT; ++c) acc[c] = (ffrag){0.f, 0.f, 0.f, 0.f};
  for (int r = 0; r < NREL; ++r) {
    const int base = b * 4097 + (sb << 9) + (r << 6);
    if (tid < 64) {
      int len = startsD[base + tid + 1] - startsD[base + tid];
      pinvL[tid] = (len > 0) ? 1.0f / (float)len : 0.0f;
    }
    const int segS = startsD[base];
    const int segE = startsD[base + 64];
    __syncthreads();          // pinvL ready; zero-init complete (first rel)
    const int nch = (segE - segS + 31) >> 5;
    ffrag aggD[4];
#pragma unroll
    for (int mt = 0; mt < 4; ++mt) aggD[mt] = (ffrag){0.f, 0.f, 0.f, 0.f};
    for (int kb = 0; kb < nch; ++kb) {
      int p = segS + (kb << 5) + ec;
      if (p < segE) {
        int rc = recI[p];
        int dl = (rc >> 17) & 63;
        uint4 g = *(const uint4*)(X + (size_t)(rc & 0x1FFFF) * 64 + ch * 8);
        unsigned short* xrow = &Xg[ec * 68 + ch * 8];
        *(uint2*)(xrow) = make_uint2(g.x, g.y);
        *(uint2*)(xrow + 4) = make_uint2(g.z, g.w);
        if (ch == 0) {        // column ec owner maintains S (self-cleaning)
          if (prev_dl >= 0) S[prev_dl * 40 + ec] = 0;
          S[dl * 40 + ec] = f2bf(pinvL[dl]);
          prev_dl = dl;
        }
      } else if (ch == 0 && prev_dl >= 0) {
        S[prev_dl * 40 + ec] = 0;
        prev_dl = -1;
      }
      __syncthreads();
      // B-frag: Xg[k][col], col = this wave's n-tile; A-frags: S rows
      const int col = (w << 4) + cl;
      bfrag xf;
#pragma unroll
      for (int j = 0; j < 8; ++j) xf[j] = (short)Xg[(kgb + j) * 68 + col];
#pragma unroll
      for (int mt = 0; mt < 4; ++mt) {
        bfrag sf = *(const bfrag*)&S[((mt << 4) + cl) * 40 + kgb];
        aggD[mt] = __builtin_amdgcn_mfma_f32_16x16x32_bf16(sf, xf, aggD[mt], 0, 0, 0);
      }
      __syncthreads();        // reads done before next chunk's stage
    }
    // aggD (wave = n-tile w) -> bf16 A-tile
#pragma unroll
    for (int mt = 0; mt < 4; ++mt)
#pragma unroll
      for (int i = 0; i < 4; ++i)
        A[((mt << 4) + ((l >> 4) << 2) + i) * 72 + (w << 4) + cl] =
            f2bf(aggD[mt][i]);
    __syncthreads();
    // verified W-mult path (wave = m-tile w): acc += A @ W_r
    bfrag a0 = *(const bfrag*)&A[((w << 4) + cl) * 72 + kgb];
    bfrag a1 = *(const bfrag*)&A[((w << 4) + cl) * 72 + 32 + kgb];
    const unsigned short* wb = Wf + ((size_t)r * CT * 2 * 64 + l) * 8;
#pragma unroll
    for (int c = 0; c < CT; ++c) {
      bfrag b0 = *(const bfrag*)(wb + (size_t)(c * 2 + 0) * 512);
      bfrag b1 = *(const bfrag*)(wb + (size_t)(c * 2 + 1) * 512);
      acc[c] = __builtin_amdgcn_mfma_f32_16x16x32_bf16(a0, b0, acc[c], 0, 0, 0);
      acc[c] = __builtin_amdgcn_mfma_f32_16x16x32_bf16(a1, b1, acc[c], 0, 0, 0);
    }
  }
  // root term (slot 8): operand = own row of X
  int arow = blk * 64 + (w << 4) + cl;
  if (arow >= N) arow = N - 1;
  const unsigned short* xp = X + (size_t)arow * 64 + kgb;
  bfrag a0 = *(const bfrag*)(xp);
  bfrag a1 = *(const bfrag*)(xp + 32);
  const unsigned short* wb = Wf + ((size_t)NREL * CT * 2 * 64 + l) * 8;
#pragma unroll
  for (int c = 0; c < CT; ++c) {
    bfrag b0 = *(const bfrag*)(wb + (size_t)(c * 2 + 0) * 512);
    bfrag b1 = *(const bfrag*)(wb + (size_t)(c * 2 + 1) * 512);
    acc[c] = __builtin_amdgcn_mfma_f32_16x16x32_bf16(a0, b0, acc[c], 0, 0, 0);
    acc[c] = __builtin_amdgcn_mfma_f32_16x16x32_bf16(a1, b1, acc[c], 0, 0, 0);
  }
  // epilogue: bias (true col = c*16 + cl), ReLU, permuted bf16 store
  float bv[CT];
#pragma unroll
  for (int c = 0; c < CT; ++c) bv[c] = bias[c * 16 + cl];
  const int rbase = blk * 64 + (w << 4) + ((l >> 4) << 2);
#pragma unroll
  for (int i = 0; i < 4; ++i) {
    int row = rbase + i;
    if (row < N) {
      float v[CT];
#pragma unroll
      for (int c = 0; c < CT; ++c) {
        v[c] = acc[c][i] + bv[c];
        if (RELU) v[c] = fmaxf(v[c], 0.f);
      }
      if (O == 64) {
        uint2 o;
        o.x = bf16pair(v[0], v[1]);
        o.y = bf16pair(v[2], v[3]);
        *(uint2*)(Y + (size_t)row * 64 + cl * 4) = o;
      } else {
        *(unsigned*)(Y + (size_t)row * 32 + cl * 2) = bf16pair(v[0], v[1]);
      }
    }
  }
}

// ---------------------------------------------------------------------------
// Decode: out[e] = dot(z[src[e]], z[dst[e]]) over 32 bf16 features (pi32-
// permuted on both operands -> invariant).
__global__ __launch_bounds__(256) void decode_kernel(
    const unsigned* __restrict__ Z, const int* __restrict__ src,
    const int* __restrict__ dst, float* __restrict__ out, int E) {
  int e = blockIdx.x * blockDim.x + threadIdx.x;
  if (e >= E) return;
  const uint4* zs = (const uint4*)(Z + (size_t)src[e] * 16);
  const uint4* zd = (const uint4*)(Z + (size_t)dst[e] * 16);
  uint4 a0 = zs[0], a1 = zs[1], a2 = zs[2], a3 = zs[3];
  uint4 b0 = zd[0], b1 = zd[1], b2 = zd[2], b3 = zd[3];
  out[e] = dot8(a0, b0) + dot8(a1, b1) + dot8(a2, b2) + dot8(a3, b3);
}

// ---------------------------------------------------------------------------
extern "C" void kernel_launch(void* const* d_in, const int* in_sizes, int n_in,
                              void* d_out, int out_size, void* d_ws, size_t ws_size,
                              hipStream_t stream) {
  const float* x     = (const float*)d_in[0];
  const float* W1    = (const float*)d_in[1];
  const float* root1 = (const float*)d_in[2];
  const float* b1    = (const float*)d_in[3];
  const float* W2    = (const float*)d_in[4];
  const float* root2 = (const float*)d_in[5];
  const float* b2    = (const float*)d_in[6];
  const int*   ei    = (const int*)d_in[7];   // [2, E] int32
  const int*   et    = (const int*)d_in[8];   // [E] int32

  const int N = in_sizes[0] / F_IN;           // 100000
  const int E = in_sizes[8];                  // 1000000
  const int nbuck = (N + 511) >> 9;           // 196
  const int nblk64 = nbuck * 8;               // 1568 (64-dst blocks)
  const int* srcp = ei;
  const int* dstp = ei + E;

  // Workspace layout (bytes), peak ~45 MB
  char* ws = (char*)d_ws;
  int*            gcur    = (int*)(ws + 0);              //  800 B [nbuck]
  unsigned*       staging = (unsigned*)(ws + 4096);      //  4.9 MB [200*SCAP]
  int*            startsD = (int*)(ws + 4919296);        //  3.2 MB [nbuck*4097]
  int*            recI    = (int*)(ws + 8131584);        //  4.9 MB [200*SCAP]
  unsigned short* wf1     = (unsigned short*)(ws + 13046784);  // 73.7 KB (9 slots)
  unsigned short* wf2     = (unsigned short*)(ws + 13120512);  // 36.9 KB (9 slots)
  unsigned short* xb      = (unsigned short*)(ws + 13157376);  // 12.8 MB bf16[N*64]
  unsigned short* hmid    = (unsigned short*)(ws + 25957376);  // 12.8 MB bf16[N*64]
  unsigned short* z       = (unsigned short*)(ws + 38757376);  //  6.4 MB bf16[N*32]

  // ---- prep (wf1, wf2, gcur) + x->bf16 + bucketed 2-pass CSR build ----
  prep_kernel<<<28, 256, 0, stream>>>(W1, root1, W2, root2, wf1, wf2, gcur, nbuck);
  cvt_bf16_kernel<<<(N * (F_IN / 8) + 255) / 256, 256, 0, stream>>>(
      x, (unsigned*)xb, N * (F_IN / 8));
  binA_kernel<<<(E + 256 * PA_PE - 1) / (256 * PA_PE), 256, 0, stream>>>(
      srcp, dstp, et, gcur, staging, E);
  binB_kernel<<<nbuck, 256, 0, stream>>>(staging, gcur, recI, startsD);

  // ---- Layer 1: xb -> hmid (bf16, pi64) ----
  ragg_kernel<F_HID, true>
      <<<nblk64, 256, 0, stream>>>(xb, wf1, startsD, recI, b1, hmid, N);

  // ---- Layer 2: hmid -> z (bf16, pi32) ----
  ragg_kernel<F_OUT, false>
      <<<nblk64, 256, 0, stream>>>(hmid, wf2, startsD, recI, b2, z, N);

  // ---- Decode ----
  decode_kernel<<<(E + 255) / 256, 256, 0, stream>>>((const unsigned*)z, srcp, dstp,
                                                     (float*)d_out, E);
}